// Round 21
// baseline (2053.019 us; speedup 1.0000x reference)
//
#include <hip/hip_runtime.h>
#include <hip/hip_bf16.h>
#include <hip/hip_fp16.h>
#include <stdint.h>

// LSTMModelLite: B=128,T=512,F=784,H=256,C=10
// R11 = R10 + issue-order surgery on the scan step (counted-vmcnt by
//   construction) + h_all dbuf (1 barrier/step).
//   R10 measured 5900cyc/step. vmcnt retires IN ISSUE ORDER, so R10's poll
//   tag-check waited for older prefetch loads AND store-acks (y stores ~HBM,
//   publish stores ~700cyc uncached) every step. Fix: issue next step's 6
//   poll loads FIRST (right after gates, before publish/y/prefetch;
//   sched_barrier pins order), carry v0..v5 across the loop, check at next
//   step top -> compiler emits a counted waitcnt (polls oldest; stores'
//   acks stay in flight) and poll latency hides under the step tail.
//   h_all[2] double-buffer removes BAR-B.
// ws: xw 134217728 | pub 262144 (overlay wt_hi, dead after gemm) |
//     wt_lo 1638400 | wfrag 524288

typedef __attribute__((ext_vector_type(8))) short short8;
typedef __attribute__((ext_vector_type(4))) float f32x4;

__device__ __forceinline__ unsigned short f2bf(float f) {
  union { float f; uint32_t u; } v; v.f = f;
  return (unsigned short)((v.u + 0x7fffu + ((v.u >> 16) & 1u)) >> 16);
}
__device__ __forceinline__ float bfu2f(uint32_t u16) {
  union { uint32_t u; float f; } v; v.u = u16 << 16; return v.f;
}
__device__ __forceinline__ float sigm(float x) {
  return __builtin_amdgcn_rcpf(1.f + __expf(-x));
}
__device__ __forceinline__ float tanh_(float x) {
  float e = __expf(2.f * x);
  return 1.f - 2.f * __builtin_amdgcn_rcpf(e + 1.f);
}
// raw barrier: waits LDS ops only; vmem (y stores, xw prefetch, pub) stays
// in flight across it. memory-clobber sandwich pins compiler ordering.
__device__ __forceinline__ void bar_raw() {
  asm volatile("s_waitcnt lgkmcnt(0)" ::: "memory");
  __builtin_amdgcn_s_barrier();
  asm volatile("" ::: "memory");
}

#define PUB_LD(p) __hip_atomic_load((p), __ATOMIC_RELAXED, __HIP_MEMORY_SCOPE_SYSTEM)
#define PUB_ST(p, v) __hip_atomic_store((p), (v), __ATOMIC_RELAXED, __HIP_MEMORY_SCOPE_SYSTEM)

__global__ void repack_w(const float* __restrict__ w, unsigned short* __restrict__ wt_hi,
                         unsigned short* __restrict__ wt_lo) {
  int idx = blockIdx.x * 256 + threadIdx.x;  // n*800 + k
  if (idx >= 1024 * 800) return;
  int n = idx / 800, k = idx - n * 800;
  float v = (k < 784) ? w[k * 1024 + n] : 0.f;
  unsigned short hi = f2bf(v);
  wt_hi[idx] = hi;
  wt_lo[idx] = f2bf(v - bfu2f(hi));
}

// rec_kernel fp32 [256 k][1024 n] -> B-frags indexed (g,w,G,ks,lane,8)
// g in [0,4): WG; w in [0,4): wave   (R4 layout, verbatim)
__global__ void repack_wf(const float* __restrict__ rk, unsigned short* __restrict__ wf) {
  int idx = blockIdx.x * 256 + threadIdx.x;  // 4g*4w*4G*8ks*64lane = 32768
  if (idx >= 32768) return;
  int lane = idx & 63, ks = (idx >> 6) & 7, G = (idx >> 9) & 3;
  int w = (idx >> 11) & 3, g = (idx >> 13) & 3;
  int ncol = G * 256 + g * 64 + 16 * w + (lane & 15);
  int kb = ks * 32 + ((lane >> 4) << 3);
  union { unsigned short s[8]; uint4 v; } u;
  #pragma unroll
  for (int e = 0; e < 8; ++e) u.s[e] = f2bf(rk[(size_t)(kb + e) * 1024 + ncol]);
  ((uint4*)wf)[idx] = u.v;
}

// ---- xw = x @ kernel ; BM=BN=128, BK=32, 256 thr, B split hi+lo (2 MFMAs) ----
__global__ __launch_bounds__(256, 2) void gemm_xw(
    const float* __restrict__ x, const unsigned short* __restrict__ wt_hi,
    const unsigned short* __restrict__ wt_lo, __half* __restrict__ xw) {
  __shared__ __align__(16) unsigned short As[128][40];
  __shared__ __align__(16) unsigned short Bh[128][40];
  __shared__ __align__(16) unsigned short Bl[128][40];
  const int tid = threadIdx.x;
  const int m0 = blockIdx.y << 7;
  const int n0 = blockIdx.x << 7;
  const int lane = tid & 63, wv = tid >> 6;
  const int wr = wv >> 1, wc = wv & 1;
  const int fm = lane & 15;
  const int fkb = (lane >> 4) << 3;
  const int sr = tid >> 1, sh = (tid & 1) << 4;
  f32x4 acc[4][4];
  #pragma unroll
  for (int a = 0; a < 4; ++a)
    #pragma unroll
    for (int b = 0; b < 4; ++b) acc[a][b] = (f32x4){0.f, 0.f, 0.f, 0.f};

  const float* xsrc = x + (size_t)(m0 + sr) * 784;
  const unsigned short* bhsrc = wt_hi + (size_t)(n0 + sr) * 800;
  const unsigned short* blsrc = wt_lo + (size_t)(n0 + sr) * 800;

  for (int kt = 0; kt < 25; ++kt) {
    const int kb = (kt << 5) + sh;
    float va[16];
    if (kb + 16 <= 784) {
      const float4* s = (const float4*)(xsrc + kb);
      #pragma unroll
      for (int q = 0; q < 4; ++q) {
        float4 f = s[q];
        va[q * 4 + 0] = f.x; va[q * 4 + 1] = f.y;
        va[q * 4 + 2] = f.z; va[q * 4 + 3] = f.w;
      }
    } else {
      #pragma unroll
      for (int q = 0; q < 16; ++q) va[q] = 0.f;
    }
    uint32_t pk[8];
    #pragma unroll
    for (int q = 0; q < 8; ++q)
      pk[q] = (uint32_t)f2bf(va[2 * q]) | ((uint32_t)f2bf(va[2 * q + 1]) << 16);
    uint4* adst = (uint4*)&As[sr][sh];
    adst[0] = make_uint4(pk[0], pk[1], pk[2], pk[3]);
    adst[1] = make_uint4(pk[4], pk[5], pk[6], pk[7]);
    const uint4* bh4 = (const uint4*)(bhsrc + kb);
    const uint4* bl4 = (const uint4*)(blsrc + kb);
    uint4* bhd = (uint4*)&Bh[sr][sh];
    uint4* bld = (uint4*)&Bl[sr][sh];
    bhd[0] = bh4[0]; bhd[1] = bh4[1];
    bld[0] = bl4[0]; bld[1] = bl4[1];
    __syncthreads();

    short8 af[4], bh[4], bl[4];
    #pragma unroll
    for (int mt = 0; mt < 4; ++mt)
      af[mt] = *(const short8*)&As[(wr << 6) + (mt << 4) + fm][fkb];
    #pragma unroll
    for (int nt = 0; nt < 4; ++nt) {
      bh[nt] = *(const short8*)&Bh[(wc << 6) + (nt << 4) + fm][fkb];
      bl[nt] = *(const short8*)&Bl[(wc << 6) + (nt << 4) + fm][fkb];
    }
    #pragma unroll
    for (int mt = 0; mt < 4; ++mt)
      #pragma unroll
      for (int nt = 0; nt < 4; ++nt) {
        acc[mt][nt] = __builtin_amdgcn_mfma_f32_16x16x32_bf16(af[mt], bh[nt], acc[mt][nt], 0, 0, 0);
        acc[mt][nt] = __builtin_amdgcn_mfma_f32_16x16x32_bf16(af[mt], bl[nt], acc[mt][nt], 0, 0, 0);
      }
    __syncthreads();
  }
  const int rbase = (lane >> 4) << 2;
  #pragma unroll
  for (int mt = 0; mt < 4; ++mt)
    #pragma unroll
    for (int nt = 0; nt < 4; ++nt) {
      int col = n0 + (wc << 6) + (nt << 4) + fm;
      #pragma unroll
      for (int r = 0; r < 4; ++r) {
        int row = m0 + (wr << 6) + (mt << 4) + rbase + r;
        xw[(size_t)row * 1024 + col] = __float2half(acc[mt][nt][r]);
      }
    }
}

// ---- persistent recurrent scan: LDS weights + early-issued batched poll ----
__global__ __launch_bounds__(256, 1) void scan_kernel(
    const unsigned short* __restrict__ wf, __half* __restrict__ xw,
    unsigned long long* __restrict__ pub,
    const float* __restrict__ bias, const float* __restrict__ wci,
    const float* __restrict__ wcf, const float* __restrict__ wco,
    const float* __restrict__ gamma, const float* __restrict__ beta,
    const float* __restrict__ mean, const float* __restrict__ var) {
  __shared__ __align__(16) unsigned short h_all[2][16][264];  // dbuf: no BAR-B
  __shared__ __align__(16) uint4 wlds[8192];  // 128 KB: Wr slice frags
  const int tid = threadIdx.x, lane = tid & 63, w = tid >> 6;
  const int gr = blockIdx.x & 7;   // batch-group
  const int g = blockIdx.x >> 3;   // member: owns jj in [0,64) -> jg = 64g+jj
  const int c = lane & 15, q = lane >> 4;
  const int jj = 16 * w + c, jg = 64 * g + jj;

  // stage this WG's Wr slice into LDS once (layout preserved from repack_wf)
  {
    const uint4* src = (const uint4*)wf + (size_t)g * 8192;
    for (int i = tid; i < 8192; i += 256) wlds[i] = src[i];
  }
  const short8* wl8 = (const short8*)wlds;

  const float b0 = bias[jg], b1 = bias[256 + jg], b2 = bias[512 + jg], b3 = bias[768 + jg];
  const float pci = wci[jg], pcf = wcf[jg], pco = wco[jg];
  const float bna = gamma[jg] * rsqrtf(var[jg] + 1e-3f);
  const float bnb = beta[jg] - mean[jg] * bna;
  float c2[4] = {0.f, 0.f, 0.f, 0.f};

  unsigned long long* mypub = pub + (size_t)(gr * 4 + g) * 512 + jj * 8 + q * 2;
  // zero own words (both parities): no garbage-tag collisions from wt_hi overlay
  PUB_ST(mypub + 0, 0ull);
  PUB_ST(mypub + 1, 0ull);
  PUB_ST(mypub + 16384, 0ull);
  PUB_ST(mypub + 16385, 0ull);

  // peer word base addresses (this thread's own 2 words per peer)
  const unsigned long long* q0 = pub + (size_t)(gr * 4 + ((g + 1) & 3)) * 512 + 2 * tid;
  const unsigned long long* q1 = pub + (size_t)(gr * 4 + ((g + 2) & 3)) * 512 + 2 * tid;
  const unsigned long long* q2 = pub + (size_t)(gr * 4 + ((g + 3) & 3)) * 512 + 2 * tid;

  const size_t xbase = ((size_t)(gr * 16 + 4 * q) << 9);  // row of batch 4q, t=0

  // prefetch xw for s=0
  float xp[4][4];
  #pragma unroll
  for (int G = 0; G < 4; ++G)
    #pragma unroll
    for (int r = 0; r < 4; ++r)
      xp[G][r] = __half2float(xw[((xbase + ((size_t)r << 9)) << 10) + G * 256 + jg]);

  __syncthreads();  // wlds staged (once; full sync fine here)

  unsigned long long v0 = 0, v1 = 0, v2 = 0, v3 = 0, v4 = 0, v5 = 0;  // carried polls

  for (int s = 0; s < 512; ++s) {
    const int par = s & 1;
    f32x4 acc[4];
    #pragma unroll
    for (int G = 0; G < 4; ++G) acc[G] = (f32x4){0.f, 0.f, 0.f, 0.f};

    if (s > 0) {
      // check carried early-issued polls first (compiler emits a COUNTED
      // waitcnt: these loads are the oldest ops in the vmem window)
      const size_t slot = (size_t)par * 16384;
      const unsigned s32 = (unsigned)s;
      bool ok = ((unsigned)(v0 >> 32) == s32) & ((unsigned)(v1 >> 32) == s32) &
                ((unsigned)(v2 >> 32) == s32) & ((unsigned)(v3 >> 32) == s32) &
                ((unsigned)(v4 >> 32) == s32) & ((unsigned)(v5 >> 32) == s32);
      long cnt = 0;
      while (!ok) {
        v0 = PUB_LD(q0 + slot);
        v1 = PUB_LD(q0 + slot + 1);
        v2 = PUB_LD(q1 + slot);
        v3 = PUB_LD(q1 + slot + 1);
        v4 = PUB_LD(q2 + slot);
        v5 = PUB_LD(q2 + slot + 1);
        ok = ((unsigned)(v0 >> 32) == s32) & ((unsigned)(v1 >> 32) == s32) &
             ((unsigned)(v2 >> 32) == s32) & ((unsigned)(v3 >> 32) == s32) &
             ((unsigned)(v4 >> 32) == s32) & ((unsigned)(v5 >> 32) == s32);
        if (++cnt > (1L << 22)) break;  // bounded: no infinite hang
      }
      // stage peer h into h_all[par] (bit = pp*2+u2 -> v[bit]; wid = 2*tid+u2)
      unsigned long long vv[6] = {v0, v1, v2, v3, v4, v5};
      #pragma unroll
      for (int pp = 0; pp < 3; ++pp) {
        int p = (g + 1 + pp) & 3;
        #pragma unroll
        for (int u2 = 0; u2 < 2; ++u2) {
          int wid = 2 * tid + u2;
          unsigned long long v = vv[pp * 2 + u2];
          int jj2 = wid >> 3, qq = (wid >> 1) & 3, uu = wid & 1;
          int m0 = 4 * qq + 2 * uu, col = 64 * p + jj2;
          h_all[par][m0][col] = (unsigned short)(v & 0xffffu);
          h_all[par][m0 + 1][col] = (unsigned short)((v >> 16) & 0xffffu);
        }
      }
      bar_raw();  // single barrier/step: h_all[par] complete before MFMA
      // z_rec = h(s) @ WrSlice — B-frags streamed from LDS (conflict-free b128)
      #pragma unroll
      for (int ks = 0; ks < 8; ++ks) {
        short8 afk = *(const short8*)&h_all[par][c][ks * 32 + q * 8];
        #pragma unroll
        for (int G = 0; G < 4; ++G) {
          short8 bfr = wl8[((w * 4 + G) * 8 + ks) * 64 + lane];
          acc[G] = __builtin_amdgcn_mfma_f32_16x16x32_bf16(afk, bfr, acc[G], 0, 0, 0);
        }
      }
      // no BAR-B: gates write h_all[par^1] (other buffer)
    }

    // gates, directly in C-layout: lane owns (jj, batches 4q..4q+3)
    float hn[4];
    #pragma unroll
    for (int r = 0; r < 4; ++r) {
      float z0 = acc[0][r] + b0 + xp[0][r];
      float z1 = acc[1][r] + b1 + xp[1][r];
      float z2 = acc[2][r] + b2 + xp[2][r];
      float z3 = acc[3][r] + b3 + xp[3][r];
      float ig = sigm(z0 + c2[r] * pci);
      float fg = sigm(z1 + c2[r] * pcf);
      float cn = fg * c2[r] + ig * tanh_(z2);
      float og = sigm(z3 + cn * pco);
      float h = og * tanh_(cn);
      c2[r] = cn;
      hn[r] = h;
    }

    if (s < 511) {
      const size_t nslot = (size_t)((s + 1) & 1) * 16384;
      // EARLY poll issue for s+1 — FIRST vmem ops of the step tail, so the
      // next-step tag check waits only on these (stores stay in flight).
      v0 = PUB_LD(q0 + nslot);
      v1 = PUB_LD(q0 + nslot + 1);
      v2 = PUB_LD(q1 + nslot);
      v3 = PUB_LD(q1 + nslot + 1);
      v4 = PUB_LD(q2 + nslot);
      v5 = PUB_LD(q2 + nslot + 1);
      __builtin_amdgcn_sched_barrier(0);  // keep stores BELOW the poll loads
      // publish h(s+1): tagged u64 pairs
      unsigned long long pv0 =
          ((unsigned long long)(unsigned)(s + 1) << 32) |
          (unsigned long long)(((uint32_t)f2bf(hn[0])) | ((uint32_t)f2bf(hn[1]) << 16));
      unsigned long long pv1 =
          ((unsigned long long)(unsigned)(s + 1) << 32) |
          (unsigned long long)(((uint32_t)f2bf(hn[2])) | ((uint32_t)f2bf(hn[3]) << 16));
      PUB_ST(mypub + nslot + 0, pv0);
      PUB_ST(mypub + nslot + 1, pv1);
    }

    // stage own h(s+1) into h_all[par^1] (read by next step's MFMA)
    #pragma unroll
    for (int r = 0; r < 4; ++r) h_all[par ^ 1][4 * q + r][jg] = f2bf(hn[r]);
    // y = tanh(BN(h)) -> xw col jg (final FC reads later)
    #pragma unroll
    for (int r = 0; r < 4; ++r) {
      float y = tanh_(hn[r] * bna + bnb);
      xw[((xbase + ((size_t)r << 9) + s) << 10) + jg] = __float2half(y);
    }
    // prefetch xw for s+1 (completes under next poll+MFMA)
    if (s < 511) {
      #pragma unroll
      for (int G = 0; G < 4; ++G)
        #pragma unroll
        for (int r = 0; r < 4; ++r)
          xp[G][r] = __half2float(
              xw[((xbase + ((size_t)r << 9) + (s + 1)) << 10) + G * 256 + jg]);
    }
  }
}

// ---- final FC: out[b,t,c] = sum_j y[b,t,j] * fcw[j,c]; wave per row ----
__global__ __launch_bounds__(256) void final_fc(const __half* __restrict__ xw,
                                                const float* __restrict__ fcw,
                                                float* __restrict__ out) {
  const int tid = threadIdx.x, lane = tid & 63, w = tid >> 6;
  const int wid = blockIdx.x * 4 + w;  // 512 waves
  float fw[4][10];
  #pragma unroll
  for (int q = 0; q < 4; ++q)
    #pragma unroll
    for (int c = 0; c < 10; ++c) fw[q][c] = fcw[(lane * 4 + q) * 10 + c];
  for (int it = 0; it < 128; ++it) {
    const int row = it * 512 + wid;
    uint2 u = *(const uint2*)(xw + ((size_t)row << 10) + lane * 4);
    const __half* hp = (const __half*)&u;
    float y0 = __half2float(hp[0]), y1 = __half2float(hp[1]);
    float y2 = __half2float(hp[2]), y3 = __half2float(hp[3]);
    float p[10];
    #pragma unroll
    for (int c = 0; c < 10; ++c)
      p[c] = y0 * fw[0][c] + y1 * fw[1][c] + y2 * fw[2][c] + y3 * fw[3][c];
    #pragma unroll
    for (int off = 1; off < 64; off <<= 1)
      #pragma unroll
      for (int c = 0; c < 10; ++c) p[c] += __shfl_xor(p[c], off, 64);
    if (lane == 0) {
      #pragma unroll
      for (int c = 0; c < 10; ++c) out[(size_t)row * 10 + c] = p[c];
    }
  }
}

extern "C" void kernel_launch(void* const* d_in, const int* in_sizes, int n_in,
                              void* d_out, int out_size, void* d_ws, size_t ws_size,
                              hipStream_t stream) {
  const float* x     = (const float*)d_in[0];
  const float* kw    = (const float*)d_in[1];
  const float* rk    = (const float*)d_in[2];
  const float* bias  = (const float*)d_in[3];
  const float* wci   = (const float*)d_in[4];
  const float* wcf   = (const float*)d_in[5];
  const float* wco   = (const float*)d_in[6];
  const float* gamma = (const float*)d_in[7];
  const float* beta  = (const float*)d_in[8];
  const float* mean  = (const float*)d_in[9];
  const float* var   = (const float*)d_in[10];
  const float* fcw   = (const float*)d_in[11];
  float* out = (float*)d_out;

  char* ws = (char*)d_ws;
  __half*         xw    = (__half*)ws;                                 // 134217728 B
  unsigned short* wt_hi = (unsigned short*)(ws + 134217728);           // 1638400 B
  unsigned short* wt_lo = (unsigned short*)(ws + 134217728 + 1638400); // 1638400 B
  unsigned short* wfrag = (unsigned short*)(ws + 134217728 + 3276800); // 524288 B
  // pub overlays wt_hi (dead after gemm_xw): 2 parity * 32 WG * 512 u64 = 262144 B
  unsigned long long* pub = (unsigned long long*)(ws + 134217728);

  repack_w<<<dim3((1024 * 800 + 255) / 256), dim3(256), 0, stream>>>(kw, wt_hi, wt_lo);
  repack_wf<<<dim3(128), dim3(256), 0, stream>>>(rk, wfrag);
  gemm_xw<<<dim3(8, 512), dim3(256), 0, stream>>>(x, wt_hi, wt_lo, xw);
  scan_kernel<<<dim3(32), dim3(256), 0, stream>>>(wfrag, xw, pub, bias,
                                                  wci, wcf, wco, gamma, beta, mean, var);
  final_fc<<<dim3(128), dim3(256), 0, stream>>>(xw, fcw, out);
}